// Round 4
// baseline (268.537 us; speedup 1.0000x reference)
//
#include <hip/hip_runtime.h>
#include <hip/hip_cooperative_groups.h>
#include <math.h>

namespace cg = cooperative_groups;

#define BB 64
#define TT 1024
#define DD 256
#define BT (BB*TT)

// ================= cooperative path =================
#define CNB 512          // blocks
#define CTPB 128         // tokens per block
#define CTPW 32          // tokens per wave
#define CPB 8            // chunks (blocks) per batch

// coop ws layout (floats)
#define CBS_OFF   0                        // [512][256] block token sums
#define CCENT_OFF (CBS_OFF + CNB*DD)       // [64][256] batch centroids
#define CDP_OFF   (CCENT_OFF + BB*DD)      // [512] d^2 partials
#define CSCAL_OFF (CDP_OFF + CNB)          // [BT][4] per-token (xy,by,y0,0)

__device__ __forceinline__ float block_reduce_256(float v) {
    __shared__ float sh[4];
    #pragma unroll
    for (int o = 32; o; o >>= 1) v += __shfl_xor(v, o, 64);
    int lane = threadIdx.x & 63, w = threadIdx.x >> 6;
    if (lane == 0) sh[w] = v;
    __syncthreads();
    float r = sh[0] + sh[1] + sh[2] + sh[3];
    __syncthreads();
    return r;
}

__global__ __launch_bounds__(256)
void kCoop(const float* __restrict__ x, const float* __restrict__ beta,
           const float* __restrict__ gamma, float* __restrict__ out,
           float* __restrict__ ws) {
    cg::grid_group grid = cg::this_grid();
    int tid = threadIdx.x, lane = tid & 63, wv = tid >> 6;
    int blk = blockIdx.x;
    float sgn0 = (lane == 0) ? -1.f : 1.f;
    int tok0 = blk * CTPB + wv * CTPW;     // this wave's first token

    // ---- phase 1: per-block token sums -> ws
    {
        const float4* xp = (const float4*)x + (size_t)tok0 * 64 + lane;
        float4 s = {0.f, 0.f, 0.f, 0.f};
        #pragma unroll 4
        for (int t = 0; t < CTPW; ++t) {
            float4 v = xp[(size_t)t * 64];
            s.x += v.x; s.y += v.y; s.z += v.z; s.w += v.w;
        }
        __shared__ float4 sh4[4][64];
        sh4[wv][lane] = s;
        __syncthreads();
        if (wv == 0) {
            float4 a = sh4[0][lane], b = sh4[1][lane], c = sh4[2][lane], d = sh4[3][lane];
            a.x += b.x + c.x + d.x;
            a.y += b.y + c.y + d.y;
            a.z += b.z + c.z + d.z;
            a.w += b.w + c.w + d.w;
            ((float4*)(ws + CBS_OFF + (size_t)blk * DD))[lane] = a;
        }
        __syncthreads();
    }
    grid.sync();

    // ---- phase 2: blocks 0..63 -> per-batch centroids
    if (blk < BB) {
        float m = 0.f;
        #pragma unroll
        for (int i = 0; i < CPB; ++i)
            m += ws[CBS_OFF + (size_t)(blk * CPB + i) * DD + tid];
        m *= (1.0f / TT);
        float dot = block_reduce_256(tid == 0 ? -m * m : m * m);
        ws[CCENT_OFF + (size_t)blk * DD + tid] = m / sqrtf(fmaxf(-dot, 1e-8f));
    }
    grid.sync();

    // ---- phase 3: every block redundantly computes mean + scalars
    __shared__ float smean[DD];
    __shared__ float ssc[4];
    {
        float a = 0.f;
        #pragma unroll 8
        for (int b = 0; b < BB; ++b) a += ws[CCENT_OFF + (size_t)b * DD + tid];
        a *= (1.0f / BB);
        float dot = block_reduce_256(tid == 0 ? -a * a : a * a);
        float mean_d = a / sqrtf(fmaxf(-dot, 1e-8f));
        smean[tid] = mean_d;
        float bt = beta[tid];
        float w_d = mean_d + bt;
        float mb  = block_reduce_256(tid == 0 ? -mean_d * bt : mean_d * bt);
        float wwp = block_reduce_256(tid == 0 ? -w_d * w_d : w_d * w_d);
        if (tid == 0) {
            ssc[0] = 1.0f / (1.0f - mb);
            ssc[1] = mb;
            ssc[2] = wwp;
            ssc[3] = mean_d;               // mean0 (tid 0 owns dim 0)
        }
        __syncthreads();
    }
    float4 m4 = ((const float4*)smean)[lane];
    float4 b4 = ((const float4*)beta)[lane];
    float invden = ssc[0], mbs = ssc[1], wws = ssc[2], mean0 = ssc[3];

    // ---- phase 4: per-token xy,by,y0 -> SCAL; d^2 block partial
    {
        const float4* xp = (const float4*)x + (size_t)tok0 * 64 + lane;
        float lsum = 0.f;
        #pragma unroll 2
        for (int t = 0; t < CTPW; ++t) {
            float4 v = xp[(size_t)t * 64];
            float pxy = sgn0 * m4.x * v.x + m4.y * v.y + m4.z * v.z + m4.w * v.w;
            float pby = sgn0 * b4.x * v.x + b4.y * v.y + b4.z * v.z + b4.w * v.w;
            #pragma unroll
            for (int o = 32; o; o >>= 1) {
                pxy += __shfl_xor(pxy, o, 64);
                pby += __shfl_xor(pby, o, 64);
            }
            if (lane == 0) {
                float4 sc; sc.x = pxy; sc.y = pby; sc.z = v.x; sc.w = 0.f;
                ((float4*)(ws + CSCAL_OFF))[tok0 + t] = sc;
            }
            float d = acoshf(fmaxf(-pxy, 1.0f + 1e-7f));
            lsum += fmaxf(d * d, 1e-8f);
        }
        __shared__ float shp[4];
        if (lane == 0) shp[wv] = lsum;
        __syncthreads();
        if (tid == 0) ws[CDP_OFF + blk] = shp[0] + shp[1] + shp[2] + shp[3];
        __syncthreads();
    }
    grid.sync();

    // ---- phase 5: redundant var -> scale; ABC epilogue; stream out
    float ps = ws[CDP_OFF + tid] + ws[CDP_OFF + 256 + tid];
    float tot = block_reduce_256(ps);
    float var = sqrtf(tot / (float)BT);
    float scale = gamma[0] / (var + 1e-5f);

    {
        const float4* xp = (const float4*)x + (size_t)tok0 * 64 + lane;
        float4* op = (float4*)out + (size_t)tok0 * 64 + lane;
        #pragma unroll 2
        for (int t = 0; t < CTPW; ++t) {
            float4 sc = ((const float4*)(ws + CSCAL_OFF))[tok0 + t];
            float xy = sc.x, by = sc.y, y0 = sc.z;

            float d   = acoshf(fmaxf(-xy, 1.0f + 1e-7f));
            float un2 = fmaxf(xy * xy - 1.0f, 1e-8f);
            float f1  = d * scale / sqrtf(un2);
            float u0  = y0 + xy * mean0;
            float en2 = f1 * f1 * (un2 + 2.0f * u0 * u0);
            float n   = sqrtf(en2);
            float factor = fminf(1.0f, 32.0f / fmaxf(n, 1e-8f));
            float ff1 = factor * f1;
            float bv  = ff1 * (by + xy * mbs);
            float coeff = bv * invden;
            float vn2 = ff1 * ff1 * un2 + 2.0f * coeff * bv + coeff * coeff * wws;
            float vn  = sqrtf(fmaxf(vn2, 1e-8f));
            float shv = sinhf(vn) / vn;
            float chv = coshf(vn);
            float A = shv * ff1;
            float B = shv * (ff1 * xy + coeff);
            float C = chv + shv * coeff;

            float4 v = xp[(size_t)t * 64];
            float4 o4;
            o4.x = A * v.x + B * m4.x + C * b4.x;
            o4.y = A * v.y + B * m4.y + C * b4.y;
            o4.z = A * v.z + B * m4.z + C * b4.z;
            o4.w = A * v.w + B * m4.w + C * b4.w;
            op[(size_t)t * 64] = o4;
        }
    }
}

// ================= fallback path (R2, proven) =================
#define SS 16
#define TPC (TT/SS)
#define PA_OFF   0
#define ABC_OFF  PA_OFF
#define MEAN_OFF (PA_OFF + 1024*DD)
#define SC_OFF   (MEAN_OFF + DD)
#define SCAL_OFF (SC_OFF + 16)
#define DP_OFF   (SCAL_OFF + BT*4)

__global__ void kA(const float* __restrict__ x, float* __restrict__ ws) {
    int chunk = blockIdx.x;
    int d = threadIdx.x;
    int b = chunk / SS, s = chunk % SS;
    const float* xp = x + (size_t)(b*TT + s*TPC) * DD + d;
    float sum = 0.f;
    #pragma unroll 8
    for (int t = 0; t < TPC; ++t) sum += xp[(size_t)t * DD];
    ws[PA_OFF + (size_t)chunk * DD + d] = sum;
}

__global__ void kB(const float* __restrict__ beta, float* __restrict__ ws) {
    int tid = threadIdx.x, lane = tid & 63, wv = tid >> 6;
    float sgn0 = (lane == 0) ? -1.f : 1.f;
    const float4* pa = (const float4*)(ws + PA_OFF);
    float4 acc = {0.f, 0.f, 0.f, 0.f};
    for (int i = 0; i < 16; ++i) {
        int b = wv * 16 + i;
        float4 m = {0.f, 0.f, 0.f, 0.f};
        const float4* pp = pa + (size_t)b * SS * 64 + lane;
        #pragma unroll
        for (int s = 0; s < SS; ++s) {
            float4 t = pp[(size_t)s * 64];
            m.x += t.x; m.y += t.y; m.z += t.z; m.w += t.w;
        }
        const float inv_tt = 1.0f / TT;
        m.x *= inv_tt; m.y *= inv_tt; m.z *= inv_tt; m.w *= inv_tt;
        float p = sgn0 * m.x * m.x + m.y * m.y + m.z * m.z + m.w * m.w;
        #pragma unroll
        for (int o = 32; o; o >>= 1) p += __shfl_xor(p, o, 64);
        float inv = 1.0f / sqrtf(fmaxf(-p, 1e-8f));
        acc.x += m.x * inv; acc.y += m.y * inv; acc.z += m.z * inv; acc.w += m.w * inv;
    }
    __shared__ float4 sh4[4][64];
    sh4[wv][lane] = acc;
    __syncthreads();
    if (wv == 0) {
        float4 a;
        a.x = sh4[0][lane].x + sh4[1][lane].x + sh4[2][lane].x + sh4[3][lane].x;
        a.y = sh4[0][lane].y + sh4[1][lane].y + sh4[2][lane].y + sh4[3][lane].y;
        a.z = sh4[0][lane].z + sh4[1][lane].z + sh4[2][lane].z + sh4[3][lane].z;
        a.w = sh4[0][lane].w + sh4[1][lane].w + sh4[2][lane].w + sh4[3][lane].w;
        const float inv_bb = 1.0f / BB;
        a.x *= inv_bb; a.y *= inv_bb; a.z *= inv_bb; a.w *= inv_bb;
        float p = sgn0 * a.x * a.x + a.y * a.y + a.z * a.z + a.w * a.w;
        #pragma unroll
        for (int o = 32; o; o >>= 1) p += __shfl_xor(p, o, 64);
        float inv = 1.0f / sqrtf(fmaxf(-p, 1e-8f));
        float4 mean4; mean4.x = a.x * inv; mean4.y = a.y * inv; mean4.z = a.z * inv; mean4.w = a.w * inv;
        float4 b4 = ((const float4*)beta)[lane];
        float4 w4; w4.x = mean4.x + b4.x; w4.y = mean4.y + b4.y; w4.z = mean4.z + b4.z; w4.w = mean4.w + b4.w;
        float mb = sgn0 * mean4.x * b4.x + mean4.y * b4.y + mean4.z * b4.z + mean4.w * b4.w;
        float wwp = sgn0 * w4.x * w4.x + w4.y * w4.y + w4.z * w4.z + w4.w * w4.w;
        #pragma unroll
        for (int o = 32; o; o >>= 1) { mb += __shfl_xor(mb, o, 64); wwp += __shfl_xor(wwp, o, 64); }
        ((float4*)(ws + MEAN_OFF))[lane] = mean4;
        if (lane == 0) {
            ws[SC_OFF + 1] = 1.0f / (1.0f - mb);
            ws[SC_OFF + 2] = mb;
            ws[SC_OFF + 3] = wwp;
            ws[SC_OFF + 4] = mean4.x;
        }
    }
}

__global__ void kC(const float* __restrict__ x, const float* __restrict__ beta,
                   float* __restrict__ ws) {
    int tid = threadIdx.x, lane = tid & 63, wv = tid >> 6;
    int gw = blockIdx.x * 4 + wv;
    int nw = gridDim.x * 4;
    float4 m4 = ((const float4*)(ws + MEAN_OFF))[lane];
    float4 b4 = ((const float4*)beta)[lane];
    float sgn0 = (lane == 0) ? -1.f : 1.f;
    float lsum = 0.f;
    for (int tok = gw; tok < BT; tok += nw) {
        float4 x4 = ((const float4*)(x + (size_t)tok * DD))[lane];
        float pxy = sgn0 * m4.x * x4.x + m4.y * x4.y + m4.z * x4.z + m4.w * x4.w;
        float pby = sgn0 * b4.x * x4.x + b4.y * x4.y + b4.z * x4.z + b4.w * x4.w;
        #pragma unroll
        for (int o = 32; o; o >>= 1) {
            pxy += __shfl_xor(pxy, o, 64);
            pby += __shfl_xor(pby, o, 64);
        }
        if (lane == 0) {
            float4 sc; sc.x = pxy; sc.y = pby; sc.z = x4.x; sc.w = 0.f;
            ((float4*)(ws + SCAL_OFF))[tok] = sc;
        }
        float arg = fmaxf(-pxy, 1.0f + 1e-7f);
        float dd = acoshf(arg);
        lsum += fmaxf(dd * dd, 1e-8f);
    }
    __shared__ float sh[4];
    if (lane == 0) sh[wv] = lsum;
    __syncthreads();
    if (tid == 0) ws[DP_OFF + blockIdx.x] = sh[0] + sh[1] + sh[2] + sh[3];
}

__global__ void kS(const float* __restrict__ gamma, float* __restrict__ ws) {
    int tid = threadIdx.x;
    float s = 0.f;
    #pragma unroll
    for (int i = tid; i < 2048; i += 256) s += ws[DP_OFF + i];
    float tot = block_reduce_256(s);
    float var = sqrtf(tot / (float)BT);
    float scale = gamma[0] / (var + 1e-5f);

    float invden = ws[SC_OFF + 1];
    float mb     = ws[SC_OFF + 2];
    float ww     = ws[SC_OFF + 3];
    float mean0  = ws[SC_OFF + 4];

    int tok = blockIdx.x * 256 + tid;
    float4 sc = ((const float4*)(ws + SCAL_OFF))[tok];
    float xy = sc.x, by = sc.y, y0 = sc.z;

    float d   = acoshf(fmaxf(-xy, 1.0f + 1e-7f));
    float un2 = fmaxf(xy * xy - 1.0f, 1e-8f);
    float f1  = d * scale / sqrtf(un2);
    float u0  = y0 + xy * mean0;
    float en2 = f1 * f1 * (un2 + 2.0f * u0 * u0);
    float n   = sqrtf(en2);
    float factor = fminf(1.0f, 32.0f / fmaxf(n, 1e-8f));
    float ff1 = factor * f1;
    float bv  = ff1 * (by + xy * mb);
    float coeff = bv * invden;
    float vn2 = ff1 * ff1 * un2 + 2.0f * coeff * bv + coeff * coeff * ww;
    float vn  = sqrtf(fmaxf(vn2, 1e-8f));
    float shv = sinhf(vn) / vn;
    float chv = coshf(vn);
    float4 abc;
    abc.x = shv * ff1;
    abc.y = shv * (ff1 * xy + coeff);
    abc.z = chv + shv * coeff;
    abc.w = 0.f;
    ((float4*)(ws + ABC_OFF))[tok] = abc;
}

__global__ void kE(const float* __restrict__ x, const float* __restrict__ beta,
                   const float* __restrict__ ws, float* __restrict__ out) {
    int tid = threadIdx.x, lane = tid & 63, wv = tid >> 6;
    int tok = blockIdx.x * 4 + wv;
    float4 m4 = ((const float4*)(ws + MEAN_OFF))[lane];
    float4 b4 = ((const float4*)beta)[lane];
    float4 abc = ((const float4*)(ws + ABC_OFF))[tok];
    float A = abc.x, B = abc.y, C = abc.z;
    float4 x4 = ((const float4*)(x + (size_t)tok * DD))[lane];
    float4 o4;
    o4.x = A * x4.x + B * m4.x + C * b4.x;
    o4.y = A * x4.y + B * m4.y + C * b4.y;
    o4.z = A * x4.z + B * m4.z + C * b4.z;
    o4.w = A * x4.w + B * m4.w + C * b4.w;
    ((float4*)(out + (size_t)tok * DD))[lane] = o4;
}

extern "C" void kernel_launch(void* const* d_in, const int* in_sizes, int n_in,
                              void* d_out, int out_size, void* d_ws, size_t ws_size,
                              hipStream_t stream) {
    const float* x     = (const float*)d_in[0];
    const float* beta  = (const float*)d_in[1];
    const float* gamma = (const float*)d_in[2];
    float* out = (float*)d_out;
    float* ws  = (float*)d_ws;

    void* args[] = { (void*)&x, (void*)&beta, (void*)&gamma, (void*)&out, (void*)&ws };
    hipError_t e = hipLaunchCooperativeKernel((const void*)kCoop, dim3(CNB), dim3(256),
                                              args, 0, stream);
    if (e != hipSuccess) {
        // proven R2 path
        kA<<<1024,   256, 0, stream>>>(x, ws);
        kB<<<1,      256, 0, stream>>>(beta, ws);
        kC<<<2048,   256, 0, stream>>>(x, beta, ws);
        kS<<<BT/256, 256, 0, stream>>>(gamma, ws);
        kE<<<BT/4,   256, 0, stream>>>(x, beta, ws, out);
    }
}

// Round 5
// 93.619 us; speedup vs baseline: 2.8684x; 2.8684x over previous
//
#include <hip/hip_runtime.h>
#include <math.h>

#define BB 64
#define TT 1024
#define DD 256
#define BT (BB*TT)
#define SS 16            // token-chunks per batch for kernel A
#define TPC (TT/SS)      // 64 tokens per chunk

// ---- workspace layout (in floats) ----
#define PA_OFF   0                       // [1024][256] chunk token sums (kA->kB1)
#define CENT_OFF (PA_OFF + 1024*DD)      // [64][256] per-batch centroids (kB1->kB2)
#define MEAN_OFF (CENT_OFF + BB*DD)      // [256] final mean
#define SC_OFF   (MEAN_OFF + DD)         // scalars: [1]=invden, [2]=mb, [3]=ww, [4]=mean0
#define SCAL_OFF (SC_OFF + 16)           // [BT][4] per-token (xy, by, y0, 0)
#define DP_OFF   (SCAL_OFF + BT*4)       // [2048] dist^2 partial sums
#define WS_FLOATS (DP_OFF + 2048)

__device__ __forceinline__ float block_reduce_256(float v) {
    __shared__ float sh[4];
    #pragma unroll
    for (int o = 32; o; o >>= 1) v += __shfl_xor(v, o, 64);
    int lane = threadIdx.x & 63, w = threadIdx.x >> 6;
    if (lane == 0) sh[w] = v;
    __syncthreads();
    float r = sh[0] + sh[1] + sh[2] + sh[3];
    __syncthreads();
    return r;
}

// ---- Kernel A: per (batch, chunk) token sums ----
__global__ void kA(const float* __restrict__ x, float* __restrict__ ws) {
    int chunk = blockIdx.x;          // 0 .. 1023
    int d = threadIdx.x;             // 0 .. 255
    int b = chunk / SS, s = chunk % SS;
    const float* xp = x + (size_t)(b*TT + s*TPC) * DD + d;
    float sum = 0.f;
    #pragma unroll 8
    for (int t = 0; t < TPC; ++t) sum += xp[(size_t)t * DD];
    ws[PA_OFF + (size_t)chunk * DD + d] = sum;
}

// ---- Kernel B1: per-batch centroid (grid = 64) ----
__global__ void kB1(float* __restrict__ ws) {
    int b = blockIdx.x, d = threadIdx.x;
    float m = 0.f;
    #pragma unroll
    for (int s = 0; s < SS; ++s) m += ws[PA_OFF + (size_t)(b*SS + s) * DD + d];
    m *= (1.0f / TT);
    float dot = block_reduce_256(d == 0 ? -m*m : m*m);
    ws[CENT_OFF + (size_t)b * DD + d] = m / sqrtf(fmaxf(-dot, 1e-8f));
}

// ---- Kernel B2: batch centroid + scalars (1 block, reads 64 KB) ----
__global__ void kB2(const float* __restrict__ beta, float* __restrict__ ws) {
    int d = threadIdx.x;
    float a = 0.f;
    #pragma unroll 8
    for (int b = 0; b < BB; ++b) a += ws[CENT_OFF + (size_t)b * DD + d];
    a *= (1.0f / BB);
    float dot = block_reduce_256(d == 0 ? -a*a : a*a);
    float mean_d = a / sqrtf(fmaxf(-dot, 1e-8f));
    ws[MEAN_OFF + d] = mean_d;
    float bt = beta[d];
    float w_d = mean_d + bt;
    float mb  = block_reduce_256(d == 0 ? -mean_d*bt : mean_d*bt);   // <mean,beta>_L
    float wwp = block_reduce_256(d == 0 ? -w_d*w_d : w_d*w_d);       // <w,w>_L
    if (d == 0) {
        ws[SC_OFF + 1] = 1.0f / (1.0f - mb);
        ws[SC_OFF + 2] = mb;
        ws[SC_OFF + 3] = wwp;
        ws[SC_OFF + 4] = mean_d;     // mean0 (d==0 owns dim 0)
    }
}

// ---- Kernel C: per-token xy=<mean,y>_L, by=<beta,y>_L, y0; d^2 partials ----
__global__ void kC(const float* __restrict__ x, const float* __restrict__ beta,
                   float* __restrict__ ws) {
    int tid = threadIdx.x, lane = tid & 63, wv = tid >> 6;
    int gw = blockIdx.x * 4 + wv;
    int nw = gridDim.x * 4;
    float4 m4 = ((const float4*)(ws + MEAN_OFF))[lane];
    float4 b4 = ((const float4*)beta)[lane];
    float sgn0 = (lane == 0) ? -1.f : 1.f;
    float lsum = 0.f;
    for (int tok = gw; tok < BT; tok += nw) {
        float4 x4 = ((const float4*)(x + (size_t)tok * DD))[lane];
        float pxy = sgn0 * m4.x * x4.x + m4.y * x4.y + m4.z * x4.z + m4.w * x4.w;
        float pby = sgn0 * b4.x * x4.x + b4.y * x4.y + b4.z * x4.z + b4.w * x4.w;
        #pragma unroll
        for (int o = 32; o; o >>= 1) {
            pxy += __shfl_xor(pxy, o, 64);
            pby += __shfl_xor(pby, o, 64);
        }
        if (lane == 0) {
            float4 sc; sc.x = pxy; sc.y = pby; sc.z = x4.x; sc.w = 0.f;
            ((float4*)(ws + SCAL_OFF))[tok] = sc;
        }
        float d = acoshf(fmaxf(-pxy, 1.0f + 1e-7f));
        lsum += fmaxf(d * d, 1e-8f);
    }
    __shared__ float sh[4];
    if (lane == 0) sh[wv] = lsum;
    __syncthreads();
    if (tid == 0) ws[DP_OFF + blockIdx.x] = sh[0] + sh[1] + sh[2] + sh[3];
}

// ---- Kernel E: redundant var reduce + closed-form ABC + stream out ----
// 512 blocks x 256 thr; each wave handles 32 consecutive tokens.
__global__ void kE(const float* __restrict__ x, const float* __restrict__ beta,
                   const float* __restrict__ gamma,
                   const float* __restrict__ ws, float* __restrict__ out) {
    int tid = threadIdx.x, lane = tid & 63, wv = tid >> 6;
    // redundant, deterministic global-var fold (8 KB from L2)
    float s = 0.f;
    #pragma unroll
    for (int i = tid; i < 2048; i += 256) s += ws[DP_OFF + i];
    float tot = block_reduce_256(s);
    float var = sqrtf(tot / (float)BT);
    float scale = gamma[0] / (var + 1e-5f);

    float invden = ws[SC_OFF + 1];
    float mbs    = ws[SC_OFF + 2];
    float wws    = ws[SC_OFF + 3];
    float mean0  = ws[SC_OFF + 4];
    float4 m4 = ((const float4*)(ws + MEAN_OFF))[lane];
    float4 b4 = ((const float4*)beta)[lane];

    int tok0 = blockIdx.x * 128 + wv * 32;
    const float4* xp = (const float4*)x + (size_t)tok0 * 64 + lane;
    float4* op = (float4*)out + (size_t)tok0 * 64 + lane;

    #pragma unroll 2
    for (int t = 0; t < 32; ++t) {
        float4 sc = ((const float4*)(ws + SCAL_OFF))[tok0 + t];  // wave-uniform broadcast
        float xy = sc.x, by = sc.y, y0 = sc.z;

        float d   = acoshf(fmaxf(-xy, 1.0f + 1e-7f));
        float un2 = fmaxf(xy * xy - 1.0f, 1e-8f);
        float f1  = d * scale / sqrtf(un2);
        float u0  = y0 + xy * mean0;
        float en2 = f1 * f1 * (un2 + 2.0f * u0 * u0);     // Euclid ||v||^2
        float n   = sqrtf(en2);
        float factor = fminf(1.0f, 32.0f / fmaxf(n, 1e-8f));
        float ff1 = factor * f1;
        float bv  = ff1 * (by + xy * mbs);                // <beta, v_f>_L
        float coeff = bv * invden;
        float vn2 = ff1 * ff1 * un2 + 2.0f * coeff * bv + coeff * coeff * wws;
        float vn  = sqrtf(fmaxf(vn2, 1e-8f));
        float shv = sinhf(vn) / vn;
        float chv = coshf(vn);
        float A = shv * ff1;                 // multiplies y
        float B = shv * (ff1 * xy + coeff);  // multiplies mean
        float C = chv + shv * coeff;         // multiplies beta

        float4 v = xp[(size_t)t * 64];
        float4 o4;
        o4.x = A * v.x + B * m4.x + C * b4.x;
        o4.y = A * v.y + B * m4.y + C * b4.y;
        o4.z = A * v.z + B * m4.z + C * b4.z;
        o4.w = A * v.w + B * m4.w + C * b4.w;
        op[(size_t)t * 64] = o4;
    }
}

extern "C" void kernel_launch(void* const* d_in, const int* in_sizes, int n_in,
                              void* d_out, int out_size, void* d_ws, size_t ws_size,
                              hipStream_t stream) {
    const float* x     = (const float*)d_in[0];
    const float* beta  = (const float*)d_in[1];
    const float* gamma = (const float*)d_in[2];
    float* out = (float*)d_out;
    float* ws  = (float*)d_ws;

    kA <<<1024, 256, 0, stream>>>(x, ws);
    kB1<<<64,   256, 0, stream>>>(ws);
    kB2<<<1,    256, 0, stream>>>(beta, ws);
    kC <<<2048, 256, 0, stream>>>(x, beta, ws);
    kE <<<512,  256, 0, stream>>>(x, beta, gamma, ws, out);
}

// Round 6
// 68.286 us; speedup vs baseline: 3.9325x; 1.3710x over previous
//
#include <hip/hip_runtime.h>
#include <math.h>

#define BB 64
#define TT 1024
#define DD 256
#define BT (BB*TT)
#define SS 16            // token-chunks per batch
#define TPC (TT/SS)      // 64 tokens per chunk

typedef float v4f __attribute__((ext_vector_type(4)));

// ---- workspace layout (in floats) ----
#define PA_OFF   0                       // [1024][256] chunk token sums (kA->kB1); dead after kB1
#define ABC_OFF  PA_OFF                  // [BT][4] per-token A,B,C (kS->kE) -- aliases PA
#define CENT_OFF (PA_OFF + 1024*DD)      // [64][256] per-batch centroids (kB1->kB2)
#define MEAN_OFF (CENT_OFF + BB*DD)      // [256] final mean
#define SC_OFF   (MEAN_OFF + DD)         // scalars: [1]=invden, [2]=mb, [3]=ww, [4]=mean0
#define SCAL_OFF (SC_OFF + 16)           // [BT][4] per-token (xy, by, y0, 0)
#define DP_OFF   (SCAL_OFF + BT*4)       // [2048] dist^2 partial sums

__device__ __forceinline__ float block_reduce_256(float v) {
    __shared__ float sh[4];
    #pragma unroll
    for (int o = 32; o; o >>= 1) v += __shfl_xor(v, o, 64);
    int lane = threadIdx.x & 63, w = threadIdx.x >> 6;
    if (lane == 0) sh[w] = v;
    __syncthreads();
    float r = sh[0] + sh[1] + sh[2] + sh[3];
    __syncthreads();
    return r;
}

// ---- Kernel A: per-chunk token sums (float4 loads; chunk = 64 consecutive tokens) ----
__global__ void kA(const float* __restrict__ x, float* __restrict__ ws) {
    int tid = threadIdx.x, lane = tid & 63, wv = tid >> 6;
    int chunk = blockIdx.x;                       // 0..1023; tokens [chunk*64, chunk*64+64)
    int tok0 = chunk * 64 + wv * 16;              // wave handles 16 tokens
    const float4* xp = (const float4*)x + (size_t)tok0 * 64 + lane;
    float4 s = {0.f, 0.f, 0.f, 0.f};
    #pragma unroll
    for (int t = 0; t < 16; ++t) {
        float4 v = xp[(size_t)t * 64];
        s.x += v.x; s.y += v.y; s.z += v.z; s.w += v.w;
    }
    __shared__ float4 sh4[4][64];
    sh4[wv][lane] = s;
    __syncthreads();
    if (wv == 0) {
        float4 a = sh4[0][lane], b = sh4[1][lane], c = sh4[2][lane], d = sh4[3][lane];
        a.x += b.x + c.x + d.x;
        a.y += b.y + c.y + d.y;
        a.z += b.z + c.z + d.z;
        a.w += b.w + c.w + d.w;
        ((float4*)(ws + PA_OFF + (size_t)chunk * DD))[lane] = a;
    }
}

// ---- Kernel B1: per-batch centroid (grid = 64) ----
__global__ void kB1(float* __restrict__ ws) {
    int b = blockIdx.x, d = threadIdx.x;
    float m = 0.f;
    #pragma unroll
    for (int s = 0; s < SS; ++s) m += ws[PA_OFF + (size_t)(b*SS + s) * DD + d];
    m *= (1.0f / TT);
    float dot = block_reduce_256(d == 0 ? -m*m : m*m);
    ws[CENT_OFF + (size_t)b * DD + d] = m / sqrtf(fmaxf(-dot, 1e-8f));
}

// ---- Kernel B2: batch centroid + scalars (1 block, reads 64 KB) ----
__global__ void kB2(const float* __restrict__ beta, float* __restrict__ ws) {
    int d = threadIdx.x;
    float a = 0.f;
    #pragma unroll 8
    for (int b = 0; b < BB; ++b) a += ws[CENT_OFF + (size_t)b * DD + d];
    a *= (1.0f / BB);
    float dot = block_reduce_256(d == 0 ? -a*a : a*a);
    float mean_d = a / sqrtf(fmaxf(-dot, 1e-8f));
    ws[MEAN_OFF + d] = mean_d;
    float bt = beta[d];
    float w_d = mean_d + bt;
    float mb  = block_reduce_256(d == 0 ? -mean_d*bt : mean_d*bt);   // <mean,beta>_L
    float wwp = block_reduce_256(d == 0 ? -w_d*w_d : w_d*w_d);       // <w,w>_L
    if (d == 0) {
        ws[SC_OFF + 1] = 1.0f / (1.0f - mb);
        ws[SC_OFF + 2] = mb;
        ws[SC_OFF + 3] = wwp;
        ws[SC_OFF + 4] = mean_d;     // mean0 (d==0 owns dim 0)
    }
}

// ---- Kernel C: per-token xy=<mean,y>_L, by=<beta,y>_L, y0; d^2 partials ----
__global__ void kC(const float* __restrict__ x, const float* __restrict__ beta,
                   float* __restrict__ ws) {
    int tid = threadIdx.x, lane = tid & 63, wv = tid >> 6;
    int gw = blockIdx.x * 4 + wv;
    int nw = gridDim.x * 4;
    float4 m4 = ((const float4*)(ws + MEAN_OFF))[lane];
    float4 b4 = ((const float4*)beta)[lane];
    float sgn0 = (lane == 0) ? -1.f : 1.f;
    float lsum = 0.f;
    for (int tok = gw; tok < BT; tok += nw) {
        float4 x4 = ((const float4*)(x + (size_t)tok * DD))[lane];
        float pxy = sgn0 * m4.x * x4.x + m4.y * x4.y + m4.z * x4.z + m4.w * x4.w;
        float pby = sgn0 * b4.x * x4.x + b4.y * x4.y + b4.z * x4.z + b4.w * x4.w;
        #pragma unroll
        for (int o = 32; o; o >>= 1) {
            pxy += __shfl_xor(pxy, o, 64);
            pby += __shfl_xor(pby, o, 64);
        }
        if (lane == 0) {
            float4 sc; sc.x = pxy; sc.y = pby; sc.z = x4.x; sc.w = 0.f;
            ((float4*)(ws + SCAL_OFF))[tok] = sc;
        }
        float d = acoshf(fmaxf(-pxy, 1.0f + 1e-7f));
        lsum += fmaxf(d * d, 1e-8f);
    }
    __shared__ float sh[4];
    if (lane == 0) sh[wv] = lsum;
    __syncthreads();
    if (tid == 0) ws[DP_OFF + blockIdx.x] = sh[0] + sh[1] + sh[2] + sh[3];
}

// ---- Kernel S: thread-per-token ABC (var reduce folded in; 64 blocks x 256 thr) ----
__global__ void kS(const float* __restrict__ gamma, float* __restrict__ ws) {
    int tid = threadIdx.x;
    float s = 0.f;
    #pragma unroll
    for (int i = tid; i < 2048; i += 256) s += ws[DP_OFF + i];
    float tot = block_reduce_256(s);
    float var = sqrtf(tot / (float)BT);
    float scale = gamma[0] / (var + 1e-5f);

    float invden = ws[SC_OFF + 1];
    float mb     = ws[SC_OFF + 2];
    float ww     = ws[SC_OFF + 3];
    float mean0  = ws[SC_OFF + 4];

    int tok = blockIdx.x * 256 + tid;
    float4 sc = ((const float4*)(ws + SCAL_OFF))[tok];
    float xy = sc.x, by = sc.y, y0 = sc.z;

    float d   = acoshf(fmaxf(-xy, 1.0f + 1e-7f));
    float un2 = fmaxf(xy * xy - 1.0f, 1e-8f);
    float f1  = d * scale / sqrtf(un2);
    float u0  = y0 + xy * mean0;
    float en2 = f1 * f1 * (un2 + 2.0f * u0 * u0);     // Euclid ||v||^2
    float n   = sqrtf(en2);
    float factor = fminf(1.0f, 32.0f / fmaxf(n, 1e-8f));
    float ff1 = factor * f1;
    float bv  = ff1 * (by + xy * mb);                 // <beta, v_f>_L
    float coeff = bv * invden;
    float vn2 = ff1 * ff1 * un2 + 2.0f * coeff * bv + coeff * coeff * ww;
    float vn  = sqrtf(fmaxf(vn2, 1e-8f));
    float shv = sinhf(vn) / vn;
    float chv = coshf(vn);
    float4 abc;
    abc.x = shv * ff1;                 // A: multiplies y
    abc.y = shv * (ff1 * xy + coeff);  // B: multiplies mean
    abc.z = chv + shv * coeff;         // C: multiplies beta
    abc.w = 0.f;
    ((float4*)(ws + ABC_OFF))[tok] = abc;
}

// ---- Kernel E: pure streaming out = A*y + B*mean + C*beta (wave/token, NT store) ----
__global__ void kE(const float* __restrict__ x, const float* __restrict__ beta,
                   const float* __restrict__ ws, float* __restrict__ out) {
    int tid = threadIdx.x, lane = tid & 63, wv = tid >> 6;
    int tok = blockIdx.x * 4 + wv;
    float4 m4 = ((const float4*)(ws + MEAN_OFF))[lane];
    float4 b4 = ((const float4*)beta)[lane];
    float4 abc = ((const float4*)(ws + ABC_OFF))[tok];
    float A = abc.x, B = abc.y, C = abc.z;
    float4 x4 = ((const float4*)(x + (size_t)tok * DD))[lane];
    v4f o4;
    o4.x = A * x4.x + B * m4.x + C * b4.x;
    o4.y = A * x4.y + B * m4.y + C * b4.y;
    o4.z = A * x4.z + B * m4.z + C * b4.z;
    o4.w = A * x4.w + B * m4.w + C * b4.w;
    __builtin_nontemporal_store(o4, (v4f*)(out + (size_t)tok * DD) + lane);
}

extern "C" void kernel_launch(void* const* d_in, const int* in_sizes, int n_in,
                              void* d_out, int out_size, void* d_ws, size_t ws_size,
                              hipStream_t stream) {
    const float* x     = (const float*)d_in[0];
    const float* beta  = (const float*)d_in[1];
    const float* gamma = (const float*)d_in[2];
    float* out = (float*)d_out;
    float* ws  = (float*)d_ws;

    kA <<<1024,   256, 0, stream>>>(x, ws);
    kB1<<<64,     256, 0, stream>>>(ws);
    kB2<<<1,      256, 0, stream>>>(beta, ws);
    kC <<<2048,   256, 0, stream>>>(x, beta, ws);
    kS <<<BT/256, 256, 0, stream>>>(gamma, ws);
    kE <<<BT/4,   256, 0, stream>>>(x, beta, ws, out);
}

// Round 7
// 67.451 us; speedup vs baseline: 3.9812x; 1.0124x over previous
//
#include <hip/hip_runtime.h>
#include <math.h>

#define BB 64
#define TT 1024
#define DD 256
#define BT (BB*TT)
#define SS 16            // token-chunks per batch
#define TPC (TT/SS)      // 64 tokens per chunk

typedef float v4f __attribute__((ext_vector_type(4)));

// ---- workspace layout (in floats) ----
#define PA_OFF   0                       // [1024][256] chunk token sums (kA->kB1)
#define CENT_OFF (PA_OFF + 1024*DD)      // [64][256] per-batch centroids (kB1->kB2)
#define MEAN_OFF (CENT_OFF + BB*DD)      // [256] final mean
#define SC_OFF   (MEAN_OFF + DD)         // scalars: [1]=invden, [2]=mb, [3]=ww, [4]=mean0
#define SCAL_OFF (SC_OFF + 16)           // [BT][4] per-token (xy, by, y0, 0)
#define DP_OFF   (SCAL_OFF + BT*4)       // [2048] dist^2 partial sums

__device__ __forceinline__ float block_reduce_256(float v) {
    __shared__ float sh[4];
    #pragma unroll
    for (int o = 32; o; o >>= 1) v += __shfl_xor(v, o, 64);
    int lane = threadIdx.x & 63, w = threadIdx.x >> 6;
    if (lane == 0) sh[w] = v;
    __syncthreads();
    float r = sh[0] + sh[1] + sh[2] + sh[3];
    __syncthreads();
    return r;
}

// ---- Kernel A: per-chunk token sums (float4 loads; chunk = 64 consecutive tokens) ----
__global__ void kA(const float* __restrict__ x, float* __restrict__ ws) {
    int tid = threadIdx.x, lane = tid & 63, wv = tid >> 6;
    int chunk = blockIdx.x;                       // 0..1023
    int tok0 = chunk * 64 + wv * 16;              // wave handles 16 tokens
    const float4* xp = (const float4*)x + (size_t)tok0 * 64 + lane;
    float4 s = {0.f, 0.f, 0.f, 0.f};
    #pragma unroll
    for (int t = 0; t < 16; ++t) {
        float4 v = xp[(size_t)t * 64];
        s.x += v.x; s.y += v.y; s.z += v.z; s.w += v.w;
    }
    __shared__ float4 sh4[4][64];
    sh4[wv][lane] = s;
    __syncthreads();
    if (wv == 0) {
        float4 a = sh4[0][lane], b = sh4[1][lane], c = sh4[2][lane], d = sh4[3][lane];
        a.x += b.x + c.x + d.x;
        a.y += b.y + c.y + d.y;
        a.z += b.z + c.z + d.z;
        a.w += b.w + c.w + d.w;
        ((float4*)(ws + PA_OFF + (size_t)chunk * DD))[lane] = a;
    }
}

// ---- Kernel B1: per-batch centroid (grid = 64) ----
__global__ void kB1(float* __restrict__ ws) {
    int b = blockIdx.x, d = threadIdx.x;
    float m = 0.f;
    #pragma unroll
    for (int s = 0; s < SS; ++s) m += ws[PA_OFF + (size_t)(b*SS + s) * DD + d];
    m *= (1.0f / TT);
    float dot = block_reduce_256(d == 0 ? -m*m : m*m);
    ws[CENT_OFF + (size_t)b * DD + d] = m / sqrtf(fmaxf(-dot, 1e-8f));
}

// ---- Kernel B2: batch centroid + scalars (1 block, reads 64 KB) ----
__global__ void kB2(const float* __restrict__ beta, float* __restrict__ ws) {
    int d = threadIdx.x;
    float a = 0.f;
    #pragma unroll 8
    for (int b = 0; b < BB; ++b) a += ws[CENT_OFF + (size_t)b * DD + d];
    a *= (1.0f / BB);
    float dot = block_reduce_256(d == 0 ? -a*a : a*a);
    float mean_d = a / sqrtf(fmaxf(-dot, 1e-8f));
    ws[MEAN_OFF + d] = mean_d;
    float bt = beta[d];
    float w_d = mean_d + bt;
    float mb  = block_reduce_256(d == 0 ? -mean_d*bt : mean_d*bt);   // <mean,beta>_L
    float wwp = block_reduce_256(d == 0 ? -w_d*w_d : w_d*w_d);       // <w,w>_L
    if (d == 0) {
        ws[SC_OFF + 1] = 1.0f / (1.0f - mb);
        ws[SC_OFF + 2] = mb;
        ws[SC_OFF + 3] = wwp;
        ws[SC_OFF + 4] = mean_d;     // mean0 (d==0 owns dim 0)
    }
}

// ---- Kernel C: per-token xy=<mean,y>_L, by=<beta,y>_L, y0; d^2 partials ----
__global__ void kC(const float* __restrict__ x, const float* __restrict__ beta,
                   float* __restrict__ ws) {
    int tid = threadIdx.x, lane = tid & 63, wv = tid >> 6;
    int gw = blockIdx.x * 4 + wv;
    int nw = gridDim.x * 4;
    float4 m4 = ((const float4*)(ws + MEAN_OFF))[lane];
    float4 b4 = ((const float4*)beta)[lane];
    float sgn0 = (lane == 0) ? -1.f : 1.f;
    float lsum = 0.f;
    for (int tok = gw; tok < BT; tok += nw) {
        float4 x4 = ((const float4*)(x + (size_t)tok * DD))[lane];
        float pxy = sgn0 * m4.x * x4.x + m4.y * x4.y + m4.z * x4.z + m4.w * x4.w;
        float pby = sgn0 * b4.x * x4.x + b4.y * x4.y + b4.z * x4.z + b4.w * x4.w;
        #pragma unroll
        for (int o = 32; o; o >>= 1) {
            pxy += __shfl_xor(pxy, o, 64);
            pby += __shfl_xor(pby, o, 64);
        }
        if (lane == 0) {
            float4 sc; sc.x = pxy; sc.y = pby; sc.z = x4.x; sc.w = 0.f;
            ((float4*)(ws + SCAL_OFF))[tok] = sc;
        }
        float d = acoshf(fmaxf(-pxy, 1.0f + 1e-7f));
        lsum += fmaxf(d * d, 1e-8f);
    }
    __shared__ float sh[4];
    if (lane == 0) sh[wv] = lsum;
    __syncthreads();
    if (tid == 0) ws[DP_OFF + blockIdx.x] = sh[0] + sh[1] + sh[2] + sh[3];
}

// ---- Kernel E: var fold + thread-per-token ABC (LDS) + stream out ----
// 1024 blocks x 256 thr; block handles 16 tokens; each wave streams 4 tokens.
__global__ void kE(const float* __restrict__ x, const float* __restrict__ beta,
                   const float* __restrict__ gamma,
                   const float* __restrict__ ws, float* __restrict__ out) {
    int tid = threadIdx.x, lane = tid & 63, wv = tid >> 6;
    int tok0 = blockIdx.x * 16;

    // deterministic global-var fold (identical order in every block -> same scale)
    float s = 0.f;
    #pragma unroll
    for (int i = tid; i < 2048; i += 256) s += ws[DP_OFF + i];
    float tot = block_reduce_256(s);
    float var = sqrtf(tot / (float)BT);
    float scale = gamma[0] / (var + 1e-5f);

    // thread-per-token ABC for this block's 16 tokens
    __shared__ float4 sabc[16];
    if (tid < 16) {
        float invden = ws[SC_OFF + 1];
        float mb     = ws[SC_OFF + 2];
        float ww     = ws[SC_OFF + 3];
        float mean0  = ws[SC_OFF + 4];
        float4 sc = ((const float4*)(ws + SCAL_OFF))[tok0 + tid];
        float xy = sc.x, by = sc.y, y0 = sc.z;

        float d   = acoshf(fmaxf(-xy, 1.0f + 1e-7f));
        float un2 = fmaxf(xy * xy - 1.0f, 1e-8f);
        float f1  = d * scale / sqrtf(un2);
        float u0  = y0 + xy * mean0;
        float en2 = f1 * f1 * (un2 + 2.0f * u0 * u0);     // Euclid ||v||^2
        float n   = sqrtf(en2);
        float factor = fminf(1.0f, 32.0f / fmaxf(n, 1e-8f));
        float ff1 = factor * f1;
        float bv  = ff1 * (by + xy * mb);                 // <beta, v_f>_L
        float coeff = bv * invden;
        float vn2 = ff1 * ff1 * un2 + 2.0f * coeff * bv + coeff * coeff * ww;
        float vn  = sqrtf(fmaxf(vn2, 1e-8f));
        float shv = sinhf(vn) / vn;
        float chv = coshf(vn);
        float4 abc;
        abc.x = shv * ff1;                 // A: multiplies y
        abc.y = shv * (ff1 * xy + coeff);  // B: multiplies mean
        abc.z = chv + shv * coeff;         // C: multiplies beta
        abc.w = 0.f;
        sabc[tid] = abc;
    }
    __syncthreads();

    float4 m4 = ((const float4*)(ws + MEAN_OFF))[lane];
    float4 b4 = ((const float4*)beta)[lane];
    const float4* xp = (const float4*)x + (size_t)(tok0 + wv * 4) * 64 + lane;
    v4f* op = (v4f*)out + (size_t)(tok0 + wv * 4) * 64 + lane;

    #pragma unroll
    for (int t = 0; t < 4; ++t) {
        float4 abc = sabc[wv * 4 + t];     // LDS broadcast
        float A = abc.x, B = abc.y, C = abc.z;
        float4 v = xp[(size_t)t * 64];
        v4f o4;
        o4.x = A * v.x + B * m4.x + C * b4.x;
        o4.y = A * v.y + B * m4.y + C * b4.y;
        o4.z = A * v.z + B * m4.z + C * b4.z;
        o4.w = A * v.w + B * m4.w + C * b4.w;
        __builtin_nontemporal_store(o4, op + (size_t)t * 64);
    }
}

extern "C" void kernel_launch(void* const* d_in, const int* in_sizes, int n_in,
                              void* d_out, int out_size, void* d_ws, size_t ws_size,
                              hipStream_t stream) {
    const float* x     = (const float*)d_in[0];
    const float* beta  = (const float*)d_in[1];
    const float* gamma = (const float*)d_in[2];
    float* out = (float*)d_out;
    float* ws  = (float*)d_ws;

    kA <<<1024,  256, 0, stream>>>(x, ws);
    kB1<<<64,    256, 0, stream>>>(ws);
    kB2<<<1,     256, 0, stream>>>(beta, ws);
    kC <<<2048,  256, 0, stream>>>(x, beta, ws);
    kE <<<BT/16, 256, 0, stream>>>(x, beta, gamma, ws, out);
}

// Round 8
// 57.743 us; speedup vs baseline: 4.6506x; 1.1681x over previous
//
#include <hip/hip_runtime.h>
#include <math.h>

#define BB 64
#define TT 1024
#define DD 256
#define BT (BB*TT)
#define SS 16            // token-chunks per batch
#define TPC (TT/SS)      // 64 tokens per chunk

typedef float v4f __attribute__((ext_vector_type(4)));

// ---- workspace layout (in floats) ----
#define PA_OFF   0                       // [1024][256] chunk token sums (kA->kB1)
#define CENT_OFF (PA_OFF + 1024*DD)      // [64][256] per-batch centroids (kB1->kB2)
#define MEAN_OFF (CENT_OFF + BB*DD)      // [256] final mean
#define SC_OFF   (MEAN_OFF + DD)         // scalars: [1]=invden, [2]=mb, [3]=ww, [4]=mean0
#define SCAL_OFF (SC_OFF + 16)           // [BT][4] per-token (xy, by, y0, 0)
#define DP_OFF   (SCAL_OFF + BT*4)       // [1024] dist^2 partial sums

__device__ __forceinline__ float block_reduce_256(float v) {
    __shared__ float sh[4];
    #pragma unroll
    for (int o = 32; o; o >>= 1) v += __shfl_xor(v, o, 64);
    int lane = threadIdx.x & 63, w = threadIdx.x >> 6;
    if (lane == 0) sh[w] = v;
    __syncthreads();
    float r = sh[0] + sh[1] + sh[2] + sh[3];
    __syncthreads();
    return r;
}

// ---- Kernel A: per-chunk token sums (float4 loads; chunk = 64 consecutive tokens) ----
__global__ void kA(const float* __restrict__ x, float* __restrict__ ws) {
    int tid = threadIdx.x, lane = tid & 63, wv = tid >> 6;
    int chunk = blockIdx.x;                       // 0..1023
    int tok0 = chunk * 64 + wv * 16;              // wave handles 16 tokens
    const float4* xp = (const float4*)x + (size_t)tok0 * 64 + lane;
    float4 s = {0.f, 0.f, 0.f, 0.f};
    #pragma unroll
    for (int t = 0; t < 16; ++t) {
        float4 v = xp[(size_t)t * 64];
        s.x += v.x; s.y += v.y; s.z += v.z; s.w += v.w;
    }
    __shared__ float4 sh4[4][64];
    sh4[wv][lane] = s;
    __syncthreads();
    if (wv == 0) {
        float4 a = sh4[0][lane], b = sh4[1][lane], c = sh4[2][lane], d = sh4[3][lane];
        a.x += b.x + c.x + d.x;
        a.y += b.y + c.y + d.y;
        a.z += b.z + c.z + d.z;
        a.w += b.w + c.w + d.w;
        ((float4*)(ws + PA_OFF + (size_t)chunk * DD))[lane] = a;
    }
}

// ---- Kernel B1: per-batch centroid (grid = 64) ----
__global__ void kB1(float* __restrict__ ws) {
    int b = blockIdx.x, d = threadIdx.x;
    float m = 0.f;
    #pragma unroll
    for (int s = 0; s < SS; ++s) m += ws[PA_OFF + (size_t)(b*SS + s) * DD + d];
    m *= (1.0f / TT);
    float dot = block_reduce_256(d == 0 ? -m*m : m*m);
    ws[CENT_OFF + (size_t)b * DD + d] = m / sqrtf(fmaxf(-dot, 1e-8f));
}

// ---- Kernel B2: batch centroid + scalars (1 block, reads 64 KB) ----
__global__ void kB2(const float* __restrict__ beta, float* __restrict__ ws) {
    int d = threadIdx.x;
    float a = 0.f;
    #pragma unroll 8
    for (int b = 0; b < BB; ++b) a += ws[CENT_OFF + (size_t)b * DD + d];
    a *= (1.0f / BB);
    float dot = block_reduce_256(d == 0 ? -a*a : a*a);
    float mean_d = a / sqrtf(fmaxf(-dot, 1e-8f));
    ws[MEAN_OFF + d] = mean_d;
    float bt = beta[d];
    float w_d = mean_d + bt;
    float mb  = block_reduce_256(d == 0 ? -mean_d*bt : mean_d*bt);   // <mean,beta>_L
    float wwp = block_reduce_256(d == 0 ? -w_d*w_d : w_d*w_d);       // <w,w>_L
    if (d == 0) {
        ws[SC_OFF + 1] = 1.0f / (1.0f - mb);
        ws[SC_OFF + 2] = mb;
        ws[SC_OFF + 3] = wwp;
        ws[SC_OFF + 4] = mean_d;     // mean0 (d==0 owns dim 0)
    }
}

// ---- Kernel C: 16-lane-group per token; xy, by, y0 + d^2 partials ----
// 1024 blocks x 256 thr; wave = 4 groups = 4 tokens/iter; 4 iters -> 64 tokens/block.
__global__ void kC(const float* __restrict__ x, const float* __restrict__ beta,
                   float* __restrict__ ws) {
    int tid = threadIdx.x, lane = tid & 63, wv = tid >> 6;
    int g  = lane >> 4;          // group within wave (0..3)
    int gl = lane & 15;          // lane within group (0..15)

    // fragments: chunk c covers dims [c*64 + gl*4, +4)
    float4 mc[4], bc[4];
    #pragma unroll
    for (int c = 0; c < 4; ++c) {
        mc[c] = ((const float4*)(ws + MEAN_OFF))[c * 16 + gl];
        bc[c] = ((const float4*)beta)[c * 16 + gl];
    }

    float lsum = 0.f;
    int tbase = blockIdx.x * 64 + wv * 16;
    #pragma unroll
    for (int it = 0; it < 4; ++it) {
        int tok = tbase + it * 4 + g;
        const float4* xq = (const float4*)(x + (size_t)tok * DD) + gl;
        float4 q0 = xq[0], q1 = xq[16], q2 = xq[32], q3 = xq[48];

        float pxy = mc[0].x*q0.x + mc[0].y*q0.y + mc[0].z*q0.z + mc[0].w*q0.w
                  + mc[1].x*q1.x + mc[1].y*q1.y + mc[1].z*q1.z + mc[1].w*q1.w
                  + mc[2].x*q2.x + mc[2].y*q2.y + mc[2].z*q2.z + mc[2].w*q2.w
                  + mc[3].x*q3.x + mc[3].y*q3.y + mc[3].z*q3.z + mc[3].w*q3.w;
        float pby = bc[0].x*q0.x + bc[0].y*q0.y + bc[0].z*q0.z + bc[0].w*q0.w
                  + bc[1].x*q1.x + bc[1].y*q1.y + bc[1].z*q1.z + bc[1].w*q1.w
                  + bc[2].x*q2.x + bc[2].y*q2.y + bc[2].z*q2.z + bc[2].w*q2.w
                  + bc[3].x*q3.x + bc[3].y*q3.y + bc[3].z*q3.z + bc[3].w*q3.w;
        if (gl == 0) {                 // Minkowski sign on dim 0
            pxy -= 2.0f * mc[0].x * q0.x;
            pby -= 2.0f * bc[0].x * q0.x;
        }
        #pragma unroll
        for (int o = 1; o < 16; o <<= 1) {   // 4-step butterfly within 16-lane group
            pxy += __shfl_xor(pxy, o, 64);
            pby += __shfl_xor(pby, o, 64);
        }
        if (gl == 0) {
            float4 sc; sc.x = pxy; sc.y = pby; sc.z = q0.x; sc.w = 0.f;
            ((float4*)(ws + SCAL_OFF))[tok] = sc;
            float d = acoshf(fmaxf(-pxy, 1.0f + 1e-7f));
            lsum += fmaxf(d * d, 1e-8f);
        }
    }
    float tot = block_reduce_256(lsum);
    if (tid == 0) ws[DP_OFF + blockIdx.x] = tot;
}

// ---- Kernel E: var fold + thread-per-token ABC (LDS) + stream out ----
// 1024 blocks x 256 thr; block handles 16 tokens; each wave streams 4 tokens.
__global__ void kE(const float* __restrict__ x, const float* __restrict__ beta,
                   const float* __restrict__ gamma,
                   const float* __restrict__ ws, float* __restrict__ out) {
    int tid = threadIdx.x, lane = tid & 63, wv = tid >> 6;
    int tok0 = blockIdx.x * 16;

    // deterministic global-var fold (identical order in every block -> same scale)
    float s = 0.f;
    #pragma unroll
    for (int i = tid; i < 1024; i += 256) s += ws[DP_OFF + i];
    float tot = block_reduce_256(s);
    float var = sqrtf(tot / (float)BT);
    float scale = gamma[0] / (var + 1e-5f);

    // thread-per-token ABC for this block's 16 tokens
    __shared__ float4 sabc[16];
    if (tid < 16) {
        float invden = ws[SC_OFF + 1];
        float mb     = ws[SC_OFF + 2];
        float ww     = ws[SC_OFF + 3];
        float mean0  = ws[SC_OFF + 4];
        float4 sc = ((const float4*)(ws + SCAL_OFF))[tok0 + tid];
        float xy = sc.x, by = sc.y, y0 = sc.z;

        float d   = acoshf(fmaxf(-xy, 1.0f + 1e-7f));
        float un2 = fmaxf(xy * xy - 1.0f, 1e-8f);
        float f1  = d * scale / sqrtf(un2);
        float u0  = y0 + xy * mean0;
        float en2 = f1 * f1 * (un2 + 2.0f * u0 * u0);     // Euclid ||v||^2
        float n   = sqrtf(en2);
        float factor = fminf(1.0f, 32.0f / fmaxf(n, 1e-8f));
        float ff1 = factor * f1;
        float bv  = ff1 * (by + xy * mb);                 // <beta, v_f>_L
        float coeff = bv * invden;
        float vn2 = ff1 * ff1 * un2 + 2.0f * coeff * bv + coeff * coeff * ww;
        float vn  = sqrtf(fmaxf(vn2, 1e-8f));
        float shv = sinhf(vn) / vn;
        float chv = coshf(vn);
        float4 abc;
        abc.x = shv * ff1;                 // A: multiplies y
        abc.y = shv * (ff1 * xy + coeff);  // B: multiplies mean
        abc.z = chv + shv * coeff;         // C: multiplies beta
        abc.w = 0.f;
        sabc[tid] = abc;
    }
    __syncthreads();

    float4 m4 = ((const float4*)(ws + MEAN_OFF))[lane];
    float4 b4 = ((const float4*)beta)[lane];
    const float4* xp = (const float4*)x + (size_t)(tok0 + wv * 4) * 64 + lane;
    v4f* op = (v4f*)out + (size_t)(tok0 + wv * 4) * 64 + lane;

    #pragma unroll
    for (int t = 0; t < 4; ++t) {
        float4 abc = sabc[wv * 4 + t];     // LDS broadcast
        float A = abc.x, B = abc.y, C = abc.z;
        float4 v = xp[(size_t)t * 64];
        v4f o4;
        o4.x = A * v.x + B * m4.x + C * b4.x;
        o4.y = A * v.y + B * m4.y + C * b4.y;
        o4.z = A * v.z + B * m4.z + C * b4.z;
        o4.w = A * v.w + B * m4.w + C * b4.w;
        __builtin_nontemporal_store(o4, op + (size_t)t * 64);
    }
}

extern "C" void kernel_launch(void* const* d_in, const int* in_sizes, int n_in,
                              void* d_out, int out_size, void* d_ws, size_t ws_size,
                              hipStream_t stream) {
    const float* x     = (const float*)d_in[0];
    const float* beta  = (const float*)d_in[1];
    const float* gamma = (const float*)d_in[2];
    float* out = (float*)d_out;
    float* ws  = (float*)d_ws;

    kA <<<1024,  256, 0, stream>>>(x, ws);
    kB1<<<64,    256, 0, stream>>>(ws);
    kB2<<<1,     256, 0, stream>>>(beta, ws);
    kC <<<1024,  256, 0, stream>>>(x, beta, ws);
    kE <<<BT/16, 256, 0, stream>>>(x, beta, gamma, ws, out);
}

// Round 9
// 55.988 us; speedup vs baseline: 4.7963x; 1.0313x over previous
//
#include <hip/hip_runtime.h>
#include <hip/hip_fp16.h>
#include <math.h>

#define BB 64
#define TT 1024
#define DD 256
#define BT (BB*TT)
#define SS 16            // token-chunks per batch
#define TPC (TT/SS)      // 64 tokens per chunk

typedef float v4f __attribute__((ext_vector_type(4)));

// ---- workspace layout (in floats) ----
#define PA_OFF   0                       // [1024][256] chunk token sums (kA->kB1)
#define CENT_OFF (PA_OFF + 1024*DD)      // [64][256] per-batch centroids (kB1->kB2)
#define MEAN_OFF (CENT_OFF + BB*DD)      // [256] final mean
#define SC_OFF   (MEAN_OFF + DD)         // scalars: [1]=invden, [2]=mb, [3]=ww, [4]=mean0
#define SCAL_OFF (SC_OFF + 16)           // [BT][4] per-token (xy, by, y0, 0)
#define DP_OFF   (SCAL_OFF + BT*4)       // [1024] dist^2 partial sums
#define XH_OFF   (DP_OFF + 1024)         // [BT*64] ushort4 fp16 copy of x (= BT*128 floats)
#define WS_BYTES_NEEDED ((size_t)(XH_OFF)*4 + (size_t)BT*64*8)

__device__ __forceinline__ float block_reduce_256(float v) {
    __shared__ float sh[4];
    #pragma unroll
    for (int o = 32; o; o >>= 1) v += __shfl_xor(v, o, 64);
    int lane = threadIdx.x & 63, w = threadIdx.x >> 6;
    if (lane == 0) sh[w] = v;
    __syncthreads();
    float r = sh[0] + sh[1] + sh[2] + sh[3];
    __syncthreads();
    return r;
}

__device__ __forceinline__ ushort4 f4toh4(float4 v) {
    ushort4 r;
    r.x = __half_as_ushort(__float2half(v.x));
    r.y = __half_as_ushort(__float2half(v.y));
    r.z = __half_as_ushort(__float2half(v.z));
    r.w = __half_as_ushort(__float2half(v.w));
    return r;
}
__device__ __forceinline__ float4 h4tof4(ushort4 h) {
    float4 r;
    r.x = __half2float(__ushort_as_half(h.x));
    r.y = __half2float(__ushort_as_half(h.y));
    r.z = __half2float(__ushort_as_half(h.z));
    r.w = __half2float(__ushort_as_half(h.w));
    return r;
}

// ---- Kernel A (fp16 path): token sums + fp16 copy ----
__global__ void kA_h(const float* __restrict__ x, float* __restrict__ ws,
                     ushort4* __restrict__ xh) {
    int tid = threadIdx.x, lane = tid & 63, wv = tid >> 6;
    int chunk = blockIdx.x;                       // 0..1023
    int tok0 = chunk * 64 + wv * 16;
    const float4* xp = (const float4*)x + (size_t)tok0 * 64 + lane;
    ushort4* hp = xh + (size_t)tok0 * 64 + lane;
    float4 s = {0.f, 0.f, 0.f, 0.f};
    #pragma unroll
    for (int t = 0; t < 16; ++t) {
        float4 v = xp[(size_t)t * 64];
        s.x += v.x; s.y += v.y; s.z += v.z; s.w += v.w;
        hp[(size_t)t * 64] = f4toh4(v);
    }
    __shared__ float4 sh4[4][64];
    sh4[wv][lane] = s;
    __syncthreads();
    if (wv == 0) {
        float4 a = sh4[0][lane], b = sh4[1][lane], c = sh4[2][lane], d = sh4[3][lane];
        a.x += b.x + c.x + d.x;
        a.y += b.y + c.y + d.y;
        a.z += b.z + c.z + d.z;
        a.w += b.w + c.w + d.w;
        ((float4*)(ws + PA_OFF + (size_t)chunk * DD))[lane] = a;
    }
}

// ---- Kernel A (f32 fallback) ----
__global__ void kA_f(const float* __restrict__ x, float* __restrict__ ws) {
    int tid = threadIdx.x, lane = tid & 63, wv = tid >> 6;
    int chunk = blockIdx.x;
    int tok0 = chunk * 64 + wv * 16;
    const float4* xp = (const float4*)x + (size_t)tok0 * 64 + lane;
    float4 s = {0.f, 0.f, 0.f, 0.f};
    #pragma unroll
    for (int t = 0; t < 16; ++t) {
        float4 v = xp[(size_t)t * 64];
        s.x += v.x; s.y += v.y; s.z += v.z; s.w += v.w;
    }
    __shared__ float4 sh4[4][64];
    sh4[wv][lane] = s;
    __syncthreads();
    if (wv == 0) {
        float4 a = sh4[0][lane], b = sh4[1][lane], c = sh4[2][lane], d = sh4[3][lane];
        a.x += b.x + c.x + d.x;
        a.y += b.y + c.y + d.y;
        a.z += b.z + c.z + d.z;
        a.w += b.w + c.w + d.w;
        ((float4*)(ws + PA_OFF + (size_t)chunk * DD))[lane] = a;
    }
}

// ---- Kernel B1: per-batch centroid (grid = 64) ----
__global__ void kB1(float* __restrict__ ws) {
    int b = blockIdx.x, d = threadIdx.x;
    float m = 0.f;
    #pragma unroll
    for (int s = 0; s < SS; ++s) m += ws[PA_OFF + (size_t)(b*SS + s) * DD + d];
    m *= (1.0f / TT);
    float dot = block_reduce_256(d == 0 ? -m*m : m*m);
    ws[CENT_OFF + (size_t)b * DD + d] = m / sqrtf(fmaxf(-dot, 1e-8f));
}

// ---- Kernel B2: batch centroid + scalars (1 block) ----
__global__ void kB2(const float* __restrict__ beta, float* __restrict__ ws) {
    int d = threadIdx.x;
    float a = 0.f;
    #pragma unroll 8
    for (int b = 0; b < BB; ++b) a += ws[CENT_OFF + (size_t)b * DD + d];
    a *= (1.0f / BB);
    float dot = block_reduce_256(d == 0 ? -a*a : a*a);
    float mean_d = a / sqrtf(fmaxf(-dot, 1e-8f));
    ws[MEAN_OFF + d] = mean_d;
    float bt = beta[d];
    float w_d = mean_d + bt;
    float mb  = block_reduce_256(d == 0 ? -mean_d*bt : mean_d*bt);
    float wwp = block_reduce_256(d == 0 ? -w_d*w_d : w_d*w_d);
    if (d == 0) {
        ws[SC_OFF + 1] = 1.0f / (1.0f - mb);
        ws[SC_OFF + 2] = mb;
        ws[SC_OFF + 3] = wwp;
        ws[SC_OFF + 4] = mean_d;
    }
}

// ---- Kernel C (fp16 path): 16-lane-group per token ----
__global__ void kC_h(const ushort4* __restrict__ xh, const float* __restrict__ beta,
                     float* __restrict__ ws) {
    int tid = threadIdx.x, lane = tid & 63, wv = tid >> 6;
    int g  = lane >> 4;
    int gl = lane & 15;

    float4 mc[4], bc[4];
    #pragma unroll
    for (int c = 0; c < 4; ++c) {
        mc[c] = ((const float4*)(ws + MEAN_OFF))[c * 16 + gl];
        bc[c] = ((const float4*)beta)[c * 16 + gl];
    }

    float lsum = 0.f;
    int tbase = blockIdx.x * 64 + wv * 16;
    #pragma unroll
    for (int it = 0; it < 4; ++it) {
        int tok = tbase + it * 4 + g;
        const ushort4* xq = xh + (size_t)tok * 64 + gl;
        float4 q0 = h4tof4(xq[0]),  q1 = h4tof4(xq[16]),
               q2 = h4tof4(xq[32]), q3 = h4tof4(xq[48]);

        float pxy = mc[0].x*q0.x + mc[0].y*q0.y + mc[0].z*q0.z + mc[0].w*q0.w
                  + mc[1].x*q1.x + mc[1].y*q1.y + mc[1].z*q1.z + mc[1].w*q1.w
                  + mc[2].x*q2.x + mc[2].y*q2.y + mc[2].z*q2.z + mc[2].w*q2.w
                  + mc[3].x*q3.x + mc[3].y*q3.y + mc[3].z*q3.z + mc[3].w*q3.w;
        float pby = bc[0].x*q0.x + bc[0].y*q0.y + bc[0].z*q0.z + bc[0].w*q0.w
                  + bc[1].x*q1.x + bc[1].y*q1.y + bc[1].z*q1.z + bc[1].w*q1.w
                  + bc[2].x*q2.x + bc[2].y*q2.y + bc[2].z*q2.z + bc[2].w*q2.w
                  + bc[3].x*q3.x + bc[3].y*q3.y + bc[3].z*q3.z + bc[3].w*q3.w;
        if (gl == 0) {
            pxy -= 2.0f * mc[0].x * q0.x;
            pby -= 2.0f * bc[0].x * q0.x;
        }
        #pragma unroll
        for (int o = 1; o < 16; o <<= 1) {
            pxy += __shfl_xor(pxy, o, 64);
            pby += __shfl_xor(pby, o, 64);
        }
        if (gl == 0) {
            float4 sc; sc.x = pxy; sc.y = pby; sc.z = q0.x; sc.w = 0.f;
            ((float4*)(ws + SCAL_OFF))[tok] = sc;
            float d = acoshf(fmaxf(-pxy, 1.0f + 1e-7f));
            lsum += fmaxf(d * d, 1e-8f);
        }
    }
    float tot = block_reduce_256(lsum);
    if (tid == 0) ws[DP_OFF + blockIdx.x] = tot;
}

// ---- Kernel C (f32 fallback) ----
__global__ void kC_f(const float* __restrict__ x, const float* __restrict__ beta,
                     float* __restrict__ ws) {
    int tid = threadIdx.x, lane = tid & 63, wv = tid >> 6;
    int g  = lane >> 4;
    int gl = lane & 15;
    float4 mc[4], bc[4];
    #pragma unroll
    for (int c = 0; c < 4; ++c) {
        mc[c] = ((const float4*)(ws + MEAN_OFF))[c * 16 + gl];
        bc[c] = ((const float4*)beta)[c * 16 + gl];
    }
    float lsum = 0.f;
    int tbase = blockIdx.x * 64 + wv * 16;
    #pragma unroll
    for (int it = 0; it < 4; ++it) {
        int tok = tbase + it * 4 + g;
        const float4* xq = (const float4*)(x + (size_t)tok * DD) + gl;
        float4 q0 = xq[0], q1 = xq[16], q2 = xq[32], q3 = xq[48];
        float pxy = mc[0].x*q0.x + mc[0].y*q0.y + mc[0].z*q0.z + mc[0].w*q0.w
                  + mc[1].x*q1.x + mc[1].y*q1.y + mc[1].z*q1.z + mc[1].w*q1.w
                  + mc[2].x*q2.x + mc[2].y*q2.y + mc[2].z*q2.z + mc[2].w*q2.w
                  + mc[3].x*q3.x + mc[3].y*q3.y + mc[3].z*q3.z + mc[3].w*q3.w;
        float pby = bc[0].x*q0.x + bc[0].y*q0.y + bc[0].z*q0.z + bc[0].w*q0.w
                  + bc[1].x*q1.x + bc[1].y*q1.y + bc[1].z*q1.z + bc[1].w*q1.w
                  + bc[2].x*q2.x + bc[2].y*q2.y + bc[2].z*q2.z + bc[2].w*q2.w
                  + bc[3].x*q3.x + bc[3].y*q3.y + bc[3].z*q3.z + bc[3].w*q3.w;
        if (gl == 0) {
            pxy -= 2.0f * mc[0].x * q0.x;
            pby -= 2.0f * bc[0].x * q0.x;
        }
        #pragma unroll
        for (int o = 1; o < 16; o <<= 1) {
            pxy += __shfl_xor(pxy, o, 64);
            pby += __shfl_xor(pby, o, 64);
        }
        if (gl == 0) {
            float4 sc; sc.x = pxy; sc.y = pby; sc.z = q0.x; sc.w = 0.f;
            ((float4*)(ws + SCAL_OFF))[tok] = sc;
            float d = acoshf(fmaxf(-pxy, 1.0f + 1e-7f));
            lsum += fmaxf(d * d, 1e-8f);
        }
    }
    float tot = block_reduce_256(lsum);
    if (tid == 0) ws[DP_OFF + blockIdx.x] = tot;
}

// ---- ABC epilogue helper (shared math) ----
__device__ __forceinline__ float4 abc_from_scal(float4 sc, float scale,
                                                float invden, float mb,
                                                float ww, float mean0) {
    float xy = sc.x, by = sc.y, y0 = sc.z;
    float d   = acoshf(fmaxf(-xy, 1.0f + 1e-7f));
    float un2 = fmaxf(xy * xy - 1.0f, 1e-8f);
    float f1  = d * scale / sqrtf(un2);
    float u0  = y0 + xy * mean0;
    float en2 = f1 * f1 * (un2 + 2.0f * u0 * u0);
    float n   = sqrtf(en2);
    float factor = fminf(1.0f, 32.0f / fmaxf(n, 1e-8f));
    float ff1 = factor * f1;
    float bv  = ff1 * (by + xy * mb);
    float coeff = bv * invden;
    float vn2 = ff1 * ff1 * un2 + 2.0f * coeff * bv + coeff * coeff * ww;
    float vn  = sqrtf(fmaxf(vn2, 1e-8f));
    float shv = sinhf(vn) / vn;
    float chv = coshf(vn);
    float4 abc;
    abc.x = shv * ff1;
    abc.y = shv * (ff1 * xy + coeff);
    abc.z = chv + shv * coeff;
    abc.w = 0.f;
    return abc;
}

// ---- Kernel E (fp16 path) ----
__global__ void kE_h(const ushort4* __restrict__ xh, const float* __restrict__ beta,
                     const float* __restrict__ gamma,
                     const float* __restrict__ ws, float* __restrict__ out) {
    int tid = threadIdx.x, lane = tid & 63, wv = tid >> 6;
    int tok0 = blockIdx.x * 16;

    float s = 0.f;
    #pragma unroll
    for (int i = tid; i < 1024; i += 256) s += ws[DP_OFF + i];
    float tot = block_reduce_256(s);
    float var = sqrtf(tot / (float)BT);
    float scale = gamma[0] / (var + 1e-5f);

    __shared__ float4 sabc[16];
    if (tid < 16) {
        float4 sc = ((const float4*)(ws + SCAL_OFF))[tok0 + tid];
        sabc[tid] = abc_from_scal(sc, scale, ws[SC_OFF + 1], ws[SC_OFF + 2],
                                  ws[SC_OFF + 3], ws[SC_OFF + 4]);
    }
    __syncthreads();

    float4 m4 = ((const float4*)(ws + MEAN_OFF))[lane];
    float4 b4 = ((const float4*)beta)[lane];
    const ushort4* xp = xh + (size_t)(tok0 + wv * 4) * 64 + lane;
    v4f* op = (v4f*)out + (size_t)(tok0 + wv * 4) * 64 + lane;

    #pragma unroll
    for (int t = 0; t < 4; ++t) {
        float4 abc = sabc[wv * 4 + t];
        float A = abc.x, B = abc.y, C = abc.z;
        float4 v = h4tof4(xp[(size_t)t * 64]);
        v4f o4;
        o4.x = A * v.x + B * m4.x + C * b4.x;
        o4.y = A * v.y + B * m4.y + C * b4.y;
        o4.z = A * v.z + B * m4.z + C * b4.z;
        o4.w = A * v.w + B * m4.w + C * b4.w;
        __builtin_nontemporal_store(o4, op + (size_t)t * 64);
    }
}

// ---- Kernel E (f32 fallback) ----
__global__ void kE_f(const float* __restrict__ x, const float* __restrict__ beta,
                     const float* __restrict__ gamma,
                     const float* __restrict__ ws, float* __restrict__ out) {
    int tid = threadIdx.x, lane = tid & 63, wv = tid >> 6;
    int tok0 = blockIdx.x * 16;
    float s = 0.f;
    #pragma unroll
    for (int i = tid; i < 1024; i += 256) s += ws[DP_OFF + i];
    float tot = block_reduce_256(s);
    float var = sqrtf(tot / (float)BT);
    float scale = gamma[0] / (var + 1e-5f);

    __shared__ float4 sabc[16];
    if (tid < 16) {
        float4 sc = ((const float4*)(ws + SCAL_OFF))[tok0 + tid];
        sabc[tid] = abc_from_scal(sc, scale, ws[SC_OFF + 1], ws[SC_OFF + 2],
                                  ws[SC_OFF + 3], ws[SC_OFF + 4]);
    }
    __syncthreads();

    float4 m4 = ((const float4*)(ws + MEAN_OFF))[lane];
    float4 b4 = ((const float4*)beta)[lane];
    const float4* xp = (const float4*)x + (size_t)(tok0 + wv * 4) * 64 + lane;
    v4f* op = (v4f*)out + (size_t)(tok0 + wv * 4) * 64 + lane;
    #pragma unroll
    for (int t = 0; t < 4; ++t) {
        float4 abc = sabc[wv * 4 + t];
        float A = abc.x, B = abc.y, C = abc.z;
        float4 v = xp[(size_t)t * 64];
        v4f o4;
        o4.x = A * v.x + B * m4.x + C * b4.x;
        o4.y = A * v.y + B * m4.y + C * b4.y;
        o4.z = A * v.z + B * m4.z + C * b4.z;
        o4.w = A * v.w + B * m4.w + C * b4.w;
        __builtin_nontemporal_store(o4, op + (size_t)t * 64);
    }
}

extern "C" void kernel_launch(void* const* d_in, const int* in_sizes, int n_in,
                              void* d_out, int out_size, void* d_ws, size_t ws_size,
                              hipStream_t stream) {
    const float* x     = (const float*)d_in[0];
    const float* beta  = (const float*)d_in[1];
    const float* gamma = (const float*)d_in[2];
    float* out = (float*)d_out;
    float* ws  = (float*)d_ws;

    if (ws_size >= WS_BYTES_NEEDED) {
        ushort4* xh = (ushort4*)(ws + XH_OFF);
        kA_h<<<1024,  256, 0, stream>>>(x, ws, xh);
        kB1 <<<64,    256, 0, stream>>>(ws);
        kB2 <<<1,     256, 0, stream>>>(beta, ws);
        kC_h<<<1024,  256, 0, stream>>>(xh, beta, ws);
        kE_h<<<BT/16, 256, 0, stream>>>(xh, beta, gamma, ws, out);
    } else {
        kA_f<<<1024,  256, 0, stream>>>(x, ws);
        kB1 <<<64,    256, 0, stream>>>(ws);
        kB2 <<<1,     256, 0, stream>>>(beta, ws);
        kC_f<<<1024,  256, 0, stream>>>(x, beta, ws);
        kE_f<<<BT/16, 256, 0, stream>>>(x, beta, gamma, ws, out);
    }
}